// Round 7
// baseline (186.655 us; speedup 1.0000x reference)
//
#include <hip/hip_runtime.h>

// Problem constants (B=2, C=256, H=W=48, d_model=256, 8 heads, d_k=32)
// Inputs/outputs fp32. Internals bf16; all three matmuls + attention on MFMA.
// Attention computes S^T (keys in C-rows, query in C-cols) so the distance
// bias is 4 consecutive elements of a precomputed E[q][m] row (one 8B load)
// and P hits LDS as vector b64 writes instead of 16 scalar writes.
#define HW 2304
#define SW 48
#define DMODEL 256
#define NHEADS 8
#define DK 32
#define BATCH 2

typedef unsigned short u16;
typedef __attribute__((ext_vector_type(8))) short short8;
typedef __attribute__((ext_vector_type(4))) float f32x4;

__device__ __forceinline__ float bf2f(u16 v) {
  union { unsigned int u; float f; } c; c.u = ((unsigned int)v) << 16; return c.f;
}
__device__ __forceinline__ float hi2f(unsigned int u) {
  union { unsigned int u; float f; } c; c.u = u & 0xffff0000u; return c.f;
}
__device__ __forceinline__ float lo2f(unsigned int u) {
  union { unsigned int u; float f; } c; c.u = u << 16; return c.f;
}
__device__ __forceinline__ u16 f2bf(float f) {
  union { unsigned int u; float f; } c; c.f = f;
  unsigned int u = c.u;
  unsigned int r = (u + 0x7FFFu + ((u >> 16) & 1u)) >> 16;
  return (u16)r;
}
// exact floor(n/48) for n in [0, 2304): magic 87382 = (2^22+32)/48
__device__ __forceinline__ int div48(int n) { return (n * 87382) >> 22; }

// ---------------------------------------------------------------------------
// E matrix: eb[q][m] = bf16( lambda * exp(-euclid_dist(q, m)) ), 2304x2304.
// Each thread computes 8 consecutive m (never straddles a row: 48%8==0).
// grid 2592, block 256.
__global__ __launch_bounds__(256) void eb_kernel(const float* __restrict__ lam_p,
                                                 u16* __restrict__ eb) {
  int id = blockIdx.x * 256 + threadIdx.x;
  size_t flat = (size_t)id * 8;
  int q = (int)(flat / HW);
  int m = (int)(flat - (size_t)q * HW);
  int y1 = div48(q), x1 = q - y1 * SW;
  int y2 = div48(m), x2 = m - y2 * SW;
  float lam = lam_p[0];
  float dy = (float)(y1 - y2);
  float dy2 = dy * dy;
  u16 o[8];
#pragma unroll
  for (int j = 0; j < 8; ++j) {
    float dx = (float)(x1 - (x2 + j));
    o[j] = f2bf(lam * __expf(-sqrtf(dy2 + dx * dx)));
  }
  *(uint4*)(eb + flat) = *(const uint4*)o;
}

// ---------------------------------------------------------------------------
// prep: [0,288) transpose x -> xt[b][n][c] bf16 ; [288,544) W fp32->bf16
// concat [q|k|v|o]. grid 544, block 256.
__global__ __launch_bounds__(256) void prep_kernel(
    const float* __restrict__ x,
    const float* __restrict__ Wq, const float* __restrict__ Wk,
    const float* __restrict__ Wv, const float* __restrict__ Wo,
    u16* __restrict__ xt, u16* __restrict__ Wb) {
  int bid = blockIdx.x;
  int t = threadIdx.x;
  if (bid < 288) {
    int b = bid / 144, r = bid % 144;
    int c0 = (r / 36) * 64, n0 = (r % 36) * 64;
    __shared__ u16 sh[64][72];
#pragma unroll
    for (int p = 0; p < 4; ++p) {
      int row = (t >> 4) + p * 16;
      int col4 = (t & 15) * 4;
      float4 v = *(const float4*)(x + (size_t)(b * DMODEL + c0 + row) * HW +
                                  n0 + col4);
      sh[col4 + 0][row] = f2bf(v.x);
      sh[col4 + 1][row] = f2bf(v.y);
      sh[col4 + 2][row] = f2bf(v.z);
      sh[col4 + 3][row] = f2bf(v.w);
    }
    __syncthreads();
#pragma unroll
    for (int q = 0; q < 2; ++q) {
      int nrow = t >> 2;
      int c8 = (t & 3) * 8 + q * 32;
      *(uint4*)(xt + (size_t)(b * HW + n0 + nrow) * DMODEL + c0 + c8) =
          *(const uint4*)&sh[nrow][c8];
    }
  } else {
    int idx = (bid - 288) * 1024 + t * 4;
    int which = idx >> 16, off = idx & 65535;
    const float* src = (which == 0) ? Wq : (which == 1) ? Wk
                       : (which == 2) ? Wv : Wo;
    float4 v = *(const float4*)(src + off);
    ushort4 ov;
    ov.x = f2bf(v.x); ov.y = f2bf(v.y); ov.z = f2bf(v.z); ov.w = f2bf(v.w);
    *(ushort4*)(Wb + idx) = ov;
  }
}

// ---------------------------------------------------------------------------
// QKV projection, LDS-free MFMA GEMM (unchanged from R5).
// grid (36, 12, 2), block 256.
__global__ __launch_bounds__(256) void qkv_kernel(
    const u16* __restrict__ Wb, const u16* __restrict__ xt,
    const float* __restrict__ bq, const float* __restrict__ bk,
    const float* __restrict__ bv,
    u16* __restrict__ qt, u16* __restrict__ ktb, u16* __restrict__ vb) {
  int t = threadIdx.x;
  int w = t >> 6, lane = t & 63, lo = lane & 15, quad = lane >> 4;
  int n0 = blockIdx.x * 64;
  int mb = blockIdx.y, b = blockIdx.z;
  int which = mb >> 2;
  int mrel0 = (mb & 3) * 64;
  const u16* A = Wb + which * 65536;
  const float* bias = (which == 0) ? bq : (which == 1) ? bk : bv;
  const u16* Bx = xt + (size_t)b * HW * DMODEL;

  f32x4 acc[4] = {{0.f, 0.f, 0.f, 0.f}, {0.f, 0.f, 0.f, 0.f},
                  {0.f, 0.f, 0.f, 0.f}, {0.f, 0.f, 0.f, 0.f}};
#pragma unroll
  for (int k0 = 0; k0 < DMODEL; k0 += 32) {
    short8 af = *(const short8*)(A + (size_t)(mrel0 + w * 16 + lo) * DMODEL +
                                 k0 + quad * 8);
#pragma unroll
    for (int nt = 0; nt < 4; ++nt) {
      short8 bf_ = *(const short8*)(Bx + (size_t)(n0 + nt * 16 + lo) * DMODEL +
                                    k0 + quad * 8);
      acc[nt] = __builtin_amdgcn_mfma_f32_16x16x32_bf16(af, bf_, acc[nt], 0, 0, 0);
    }
  }

  int mbase = mrel0 + w * 16 + quad * 4;
  if (which == 2) {
#pragma unroll
    for (int reg = 0; reg < 4; ++reg) {
      int mrel = mbase + reg;
      float bi = bias[mrel];
      u16* dst = vb + (size_t)(b * DMODEL + mrel) * HW + n0 + lo;
#pragma unroll
      for (int nt = 0; nt < 4; ++nt) dst[nt * 16] = f2bf(acc[nt][reg] + bi);
    }
  } else {
    float sc = (which == 0) ? 0.17677669529663687f : 1.0f;
    int h = mbase >> 5, d0 = mbase & 31;
    u16* base = ((which == 0) ? qt : ktb) + (size_t)(b * NHEADS + h) * HW * DK;
    float bi[4], dv[4];
    bool usecos[4], usey[4];
#pragma unroll
    for (int reg = 0; reg < 4; ++reg) {
      int mrel = mbase + reg;
      bi[reg] = bias[mrel];
      int oo = mrel & 127;
      dv[reg] = expf(-0.07195578415606394f * (float)(oo & ~1));
      usecos[reg] = (oo & 1);
      usey[reg] = (mrel >= 128);
    }
#pragma unroll
    for (int nt = 0; nt < 4; ++nt) {
      int n = n0 + nt * 16 + lo;
      int yy = div48(n), xx = n - yy * SW;
      ushort4 ov;
      float vals[4];
#pragma unroll
      for (int reg = 0; reg < 4; ++reg) {
        float tv = (usey[reg] ? (float)yy : (float)xx) * dv[reg];
        float pe = usecos[reg] ? cosf(tv) : sinf(tv);
        vals[reg] = (acc[nt][reg] + bi[reg] + pe) * sc;
      }
      ov.x = f2bf(vals[0]); ov.y = f2bf(vals[1]);
      ov.z = f2bf(vals[2]); ov.w = f2bf(vals[3]);
      *(ushort4*)(base + (size_t)n * DK + d0) = ov;
    }
  }
}

// ---------------------------------------------------------------------------
// MFMA flash attention, S^T orientation, fixed-max softmax.
// Block = (b, h, 64-query tile), 4 waves; wave owns 16 queries (lane lo = q).
// Per key-tile: stage K/V in LDS (R5 structure), 4 QK^T mfma (S^T: key rows,
// query cols), bias via one 8B E-row load per 16-key tile, P -> LDS via b64
// vector writes, 4 PV mfma producing O^T (d rows, q cols).
// grid (36, 8, 2), block 256.
__global__ __launch_bounds__(256) void attn_kernel(
    const u16* __restrict__ qt, const u16* __restrict__ ktb,
    const u16* __restrict__ vb, const u16* __restrict__ eb,
    u16* __restrict__ aot) {
  int t = threadIdx.x;
  int w = t >> 6;
  int lane = t & 63;
  int lo = lane & 15, quad = lane >> 4;
  int n0 = blockIdx.x * 64;
  int h = blockIdx.y, b = blockIdx.z;

  __shared__ u16 Ks[64 * 40];      // [key m][d], pad 40
  __shared__ u16 Vs[32 * 72];      // [dd][m], pad 72
  __shared__ u16 Ps[4 * 16 * 72];  // per-wave [q][m], pad 72

  const u16* qtg = qt + (size_t)(b * NHEADS + h) * HW * DK;
  const u16* ktg = ktb + (size_t)(b * NHEADS + h) * HW * DK;
  const u16* vbg = vb + (size_t)(b * DMODEL + h * DK) * HW;

  // Q fragment (B-operand): lane lo = query col, k = quad*8+j
  int q = n0 + w * 16 + lo;
  short8 qf = *(const short8*)(qtg + (size_t)q * DK + quad * 8);
  const u16* ebq = eb + (size_t)q * HW;  // bias row for this lane's query

  f32x4 ot0 = {0.f, 0.f, 0.f, 0.f}, ot1 = {0.f, 0.f, 0.f, 0.f};
  float lsum = 0.f;
  u16* psw = Ps + w * 16 * 72;

  for (int kt = 0; kt < 36; ++kt) {
    int m0 = kt * 64;
    __syncthreads();  // prev PV reads done before restaging
    {  // stage K tile 64x32 and V tile 32x64 (coalesced 16B)
      int row = t >> 2, c8 = (t & 3) * 8;
      *(uint4*)&Ks[row * 40 + c8] =
          *(const uint4*)(ktg + (size_t)(m0 + row) * DK + c8);
      int dd = t >> 3, mo = (t & 7) * 8;
      *(uint4*)&Vs[dd * 72 + mo] =
          *(const uint4*)(vbg + (size_t)dd * HW + m0 + mo);
    }
    __syncthreads();

    // bias packs: 4 consecutive E values per 16-key tile (aligned 8B loads)
    uint2 ebv[4];
#pragma unroll
    for (int t4 = 0; t4 < 4; ++t4)
      ebv[t4] = *(const uint2*)(ebq + m0 + t4 * 16 + quad * 4);

    // S^T = K Q^T : A = K-frag (key rows), B = Q-frag (query cols)
    f32x4 s[4];
#pragma unroll
    for (int t4 = 0; t4 < 4; ++t4) {
      short8 kf = *(const short8*)&Ks[(t4 * 16 + lo) * 40 + quad * 8];
      f32x4 z = {0.f, 0.f, 0.f, 0.f};
      s[t4] = __builtin_amdgcn_mfma_f32_16x16x32_bf16(kf, qf, z, 0, 0, 0);
    }
    // P = exp(S + bias); rowsum; store P[q][m] as one b64 per tile
#pragma unroll
    for (int t4 = 0; t4 < 4; ++t4) {
      float p0 = __expf(s[t4][0] + lo2f(ebv[t4].x));
      float p1 = __expf(s[t4][1] + hi2f(ebv[t4].x));
      float p2 = __expf(s[t4][2] + lo2f(ebv[t4].y));
      float p3 = __expf(s[t4][3] + hi2f(ebv[t4].y));
      lsum += (p0 + p1) + (p2 + p3);
      ushort4 pk;
      pk.x = f2bf(p0); pk.y = f2bf(p1); pk.z = f2bf(p2); pk.w = f2bf(p3);
      *(ushort4*)&psw[lo * 72 + t4 * 16 + quad * 4] = pk;
    }
    // O^T += V^T P^T : A = V^T-frag (d rows), B = P-frag (query cols)
#pragma unroll
    for (int ks = 0; ks < 2; ++ks) {
      short8 pf = *(const short8*)&psw[lo * 72 + ks * 32 + quad * 8];
      short8 v0 = *(const short8*)&Vs[lo * 72 + ks * 32 + quad * 8];
      ot0 = __builtin_amdgcn_mfma_f32_16x16x32_bf16(v0, pf, ot0, 0, 0, 0);
      short8 v1 = *(const short8*)&Vs[(16 + lo) * 72 + ks * 32 + quad * 8];
      ot1 = __builtin_amdgcn_mfma_f32_16x16x32_bf16(v1, pf, ot1, 0, 0, 0);
    }
  }

  // full rowsum for this lane's query: reduce across the 4 quads
  lsum += __shfl_xor(lsum, 16);
  lsum += __shfl_xor(lsum, 32);
  float inv = 1.0f / lsum;

  // write aot[b][q][h*32 + d] (bf16): O^T rows d = dtile*16+quad*4+reg
  u16* aog = aot + (size_t)b * HW * DMODEL + (size_t)q * DMODEL + h * DK;
  ushort4 s0, s1;
  s0.x = f2bf(ot0[0] * inv); s0.y = f2bf(ot0[1] * inv);
  s0.z = f2bf(ot0[2] * inv); s0.w = f2bf(ot0[3] * inv);
  s1.x = f2bf(ot1[0] * inv); s1.y = f2bf(ot1[1] * inv);
  s1.z = f2bf(ot1[2] * inv); s1.w = f2bf(ot1[3] * inv);
  *(ushort4*)(aog + quad * 4) = s0;
  *(ushort4*)(aog + 16 + quad * 4) = s1;
}

// ---------------------------------------------------------------------------
// out[b][c][n] = x + gamma * (Wo ao)[c][n] + bo[c], LDS-free MFMA GEMM.
// grid (36, 4, 2), block 256.
__global__ __launch_bounds__(256) void out_kernel(
    const float* __restrict__ x, const u16* __restrict__ Wob,
    const float* __restrict__ bo, const float* __restrict__ gp,
    const u16* __restrict__ aot, float* __restrict__ out) {
  int t = threadIdx.x;
  int w = t >> 6, lane = t & 63, lo = lane & 15, quad = lane >> 4;
  int n0 = blockIdx.x * 64;
  int c0 = blockIdx.y * 64;
  int b = blockIdx.z;
  float gamma = gp[0];
  const u16* Ba = aot + (size_t)b * HW * DMODEL;

  f32x4 acc[4] = {{0.f, 0.f, 0.f, 0.f}, {0.f, 0.f, 0.f, 0.f},
                  {0.f, 0.f, 0.f, 0.f}, {0.f, 0.f, 0.f, 0.f}};
#pragma unroll
  for (int k0 = 0; k0 < DMODEL; k0 += 32) {
    short8 af = *(const short8*)(Wob + (size_t)(c0 + w * 16 + lo) * DMODEL +
                                 k0 + quad * 8);
#pragma unroll
    for (int nt = 0; nt < 4; ++nt) {
      short8 bf_ = *(const short8*)(Ba + (size_t)(n0 + nt * 16 + lo) * DMODEL +
                                    k0 + quad * 8);
      acc[nt] = __builtin_amdgcn_mfma_f32_16x16x32_bf16(af, bf_, acc[nt], 0, 0, 0);
    }
  }

#pragma unroll
  for (int reg = 0; reg < 4; ++reg) {
    int c = c0 + w * 16 + quad * 4 + reg;
    float bi = bo[c];
    const float* xs = x + (size_t)(b * DMODEL + c) * HW + n0 + lo;
    float* os = out + (size_t)(b * DMODEL + c) * HW + n0 + lo;
#pragma unroll
    for (int nt = 0; nt < 4; ++nt)
      os[nt * 16] = xs[nt * 16] + gamma * acc[nt][reg] + bi;
  }
}

// ---------------------------------------------------------------------------
extern "C" void kernel_launch(void* const* d_in, const int* in_sizes, int n_in,
                              void* d_out, int out_size, void* d_ws,
                              size_t ws_size, hipStream_t stream) {
  const float* x   = (const float*)d_in[0];
  const float* Wq  = (const float*)d_in[1];
  const float* bq  = (const float*)d_in[2];
  const float* Wk  = (const float*)d_in[3];
  const float* bk  = (const float*)d_in[4];
  const float* Wv  = (const float*)d_in[5];
  const float* bv  = (const float*)d_in[6];
  const float* Wo  = (const float*)d_in[7];
  const float* bo  = (const float*)d_in[8];
  const float* lam = (const float*)d_in[9];
  const float* gam = (const float*)d_in[10];

  // ws layout (bytes), total ~19.7 MB (R0 evidence: clean run through 21.3 MB):
  //   (unused)   [0, 36864)
  //   Wb    bf16 [36864, 561152)       4*65536*2, [q|k|v|o]
  //   xt    bf16 [561152, 2920448)     aliased with aot (sequential lifetime)
  //   qt    bf16 [2920448, 5279744)
  //   ktb   bf16 [5279744, 7639040)
  //   vb    bf16 [7639040, 9998336)
  //   eb    bf16 [9998336, 20615168)   2304*2304 distance-bias matrix
  char* wsb = (char*)d_ws;
  u16* Wb  = (u16*)(wsb + 36864);
  u16* xt  = (u16*)(wsb + 561152);
  u16* aot = xt;  // alias, sequential lifetime
  u16* qt  = (u16*)(wsb + 2920448);
  u16* ktb = (u16*)(wsb + 5279744);
  u16* vb  = (u16*)(wsb + 7639040);
  u16* eb  = (u16*)(wsb + 9998336);
  float* out = (float*)d_out;

  eb_kernel<<<dim3(2592), 256, 0, stream>>>(lam, eb);
  prep_kernel<<<dim3(544), 256, 0, stream>>>(x, Wq, Wk, Wv, Wo, xt, Wb);
  qkv_kernel<<<dim3(36, 12, BATCH), 256, 0, stream>>>(Wb, xt, bq, bk, bv,
                                                      qt, ktb, vb);
  attn_kernel<<<dim3(36, NHEADS, BATCH), 256, 0, stream>>>(qt, ktb, vb, eb,
                                                           aot);
  out_kernel<<<dim3(36, 4, BATCH), 256, 0, stream>>>(x, Wb + 3 * 65536, bo, gam,
                                                     aot, out);
}

// Round 8
// 152.010 us; speedup vs baseline: 1.2279x; 1.2279x over previous
//
#include <hip/hip_runtime.h>

// Problem constants (B=2, C=256, H=W=48, d_model=256, 8 heads, d_k=32)
// Inputs/outputs fp32. Internals bf16; all matmuls + attention on MFMA.
// Wb / xt / aot live in MFMA-fragment-order swizzle:
//   addr(row,k) = (row>>4)*4096 + (k>>3)*128 + (row&15)*8 + (k&7)
// so every A/B fragment wave-load is 1KB fully contiguous.
#define HW 2304
#define SW 48
#define DMODEL 256
#define NHEADS 8
#define DK 32
#define BATCH 2

typedef unsigned short u16;
typedef __attribute__((ext_vector_type(8))) short short8;
typedef __attribute__((ext_vector_type(4))) float f32x4;

__device__ __forceinline__ float bf2f(u16 v) {
  union { unsigned int u; float f; } c; c.u = ((unsigned int)v) << 16; return c.f;
}
__device__ __forceinline__ u16 f2bf(float f) {
  union { unsigned int u; float f; } c; c.f = f;
  unsigned int u = c.u;
  unsigned int r = (u + 0x7FFFu + ((u >> 16) & 1u)) >> 16;
  return (u16)r;
}
// exact floor(n/48) for n in [0, 2304): magic 87382 = (2^22+32)/48
__device__ __forceinline__ int div48(int n) { return (n * 87382) >> 22; }
// fragment-order swizzle for a [rows][256] bf16 matrix
__device__ __forceinline__ int swz(int row, int k) {
  return ((row >> 4) << 12) + ((k >> 3) << 7) + ((row & 15) << 3) + (k & 7);
}

#define DTAB_N 9032  // 95*95 = 9025, padded to multiple of 8

// ---------------------------------------------------------------------------
// prep: [0,288) transpose x -> xt (swizzled, row=n, k=c) bf16 ;
// [288,544) W fp32->bf16 swizzled, concat [q|k|v|o] ; [544,580) dtab bf16.
// grid 580, block 256.
__global__ __launch_bounds__(256) void prep_kernel(
    const float* __restrict__ x,
    const float* __restrict__ Wq, const float* __restrict__ Wk,
    const float* __restrict__ Wv, const float* __restrict__ Wo,
    const float* __restrict__ lam_p,
    u16* __restrict__ xt, u16* __restrict__ Wb, u16* __restrict__ dtabb) {
  int bid = blockIdx.x;
  int t = threadIdx.x;
  if (bid < 288) {
    int b = bid / 144, r = bid % 144;
    int c0 = (r / 36) * 64, n0 = (r % 36) * 64;
    __shared__ u16 sh[64][72];  // [n][c]
#pragma unroll
    for (int p = 0; p < 4; ++p) {
      int row = (t >> 4) + p * 16;   // c
      int col4 = (t & 15) * 4;       // n
      float4 v = *(const float4*)(x + (size_t)(b * DMODEL + c0 + row) * HW +
                                  n0 + col4);
      sh[col4 + 0][row] = f2bf(v.x);
      sh[col4 + 1][row] = f2bf(v.y);
      sh[col4 + 2][row] = f2bf(v.z);
      sh[col4 + 3][row] = f2bf(v.w);
    }
    __syncthreads();
    u16* xtb = xt + (size_t)b * HW * DMODEL;
#pragma unroll
    for (int q = 0; q < 2; ++q) {
      int nrow = t >> 2;
      int c8 = (t & 3) * 8 + q * 32;
      *(uint4*)(xtb + swz(n0 + nrow, c0 + c8)) = *(const uint4*)&sh[nrow][c8];
    }
  } else if (bid < 544) {
    int idx = (bid - 288) * 1024 + t * 4;
    int which = idx >> 16, off = idx & 65535;
    int m = off >> 8, k = off & 255;
    const float* src = (which == 0) ? Wq : (which == 1) ? Wk
                       : (which == 2) ? Wv : Wo;
    float4 v = *(const float4*)(src + off);
    ushort4 ov;
    ov.x = f2bf(v.x); ov.y = f2bf(v.y); ov.z = f2bf(v.z); ov.w = f2bf(v.w);
    *(ushort4*)(Wb + which * 65536 + swz(m, k)) = ov;
  } else {
    int id = (bid - 544) * 256 + t;
    if (id < DTAB_N) {
      float v = 0.f;
      if (id < 95 * 95) {
        float lam = lam_p[0];
        int dyi = id / 95, dxi = id - dyi * 95;
        float dy = (float)(dyi - 47), dx = (float)(dxi - 47);
        v = lam * expf(-sqrtf(dy * dy + dx * dx));
      }
      dtabb[id] = f2bf(v);
    }
  }
}

// ---------------------------------------------------------------------------
// QKV projection, LDS-free MFMA GEMM with swizzled (fully coalesced) frag
// loads. grid (36, 12, 2), block 256.
__global__ __launch_bounds__(256) void qkv_kernel(
    const u16* __restrict__ Wb, const u16* __restrict__ xt,
    const float* __restrict__ bq, const float* __restrict__ bk,
    const float* __restrict__ bv,
    u16* __restrict__ qt, u16* __restrict__ ktb, u16* __restrict__ vb) {
  int t = threadIdx.x;
  int w = t >> 6, lane = t & 63, lo = lane & 15, quad = lane >> 4;
  int n0 = blockIdx.x * 64;
  int mb = blockIdx.y, b = blockIdx.z;
  int which = mb >> 2;
  int mrel0 = (mb & 3) * 64;
  const u16* A = Wb + which * 65536 + ((mrel0 + w * 16) >> 4) * 4096 + lo * 8;
  const float* bias = (which == 0) ? bq : (which == 1) ? bk : bv;
  const u16* Bx = xt + (size_t)b * HW * DMODEL + lo * 8;

  f32x4 acc[4] = {{0.f, 0.f, 0.f, 0.f}, {0.f, 0.f, 0.f, 0.f},
                  {0.f, 0.f, 0.f, 0.f}, {0.f, 0.f, 0.f, 0.f}};
#pragma unroll
  for (int k0 = 0; k0 < DMODEL; k0 += 32) {
    int kblk = ((k0 >> 3) + quad) << 7;
    short8 af = *(const short8*)(A + kblk);
#pragma unroll
    for (int nt = 0; nt < 4; ++nt) {
      short8 bf_ = *(const short8*)(Bx + ((n0 + nt * 16) >> 4) * 4096 + kblk);
      acc[nt] = __builtin_amdgcn_mfma_f32_16x16x32_bf16(af, bf_, acc[nt], 0, 0, 0);
    }
  }

  int mbase = mrel0 + w * 16 + quad * 4;
  if (which == 2) {
#pragma unroll
    for (int reg = 0; reg < 4; ++reg) {
      int mrel = mbase + reg;
      float bi = bias[mrel];
      u16* dst = vb + (size_t)(b * DMODEL + mrel) * HW + n0 + lo;
#pragma unroll
      for (int nt = 0; nt < 4; ++nt) dst[nt * 16] = f2bf(acc[nt][reg] + bi);
    }
  } else {
    float sc = (which == 0) ? 0.17677669529663687f : 1.0f;
    int h = mbase >> 5, d0 = mbase & 31;
    u16* base = ((which == 0) ? qt : ktb) + (size_t)(b * NHEADS + h) * HW * DK;
    float bi[4], dv[4];
    bool usecos[4], usey[4];
#pragma unroll
    for (int reg = 0; reg < 4; ++reg) {
      int mrel = mbase + reg;
      bi[reg] = bias[mrel];
      int oo = mrel & 127;
      dv[reg] = expf(-0.07195578415606394f * (float)(oo & ~1));
      usecos[reg] = (oo & 1);
      usey[reg] = (mrel >= 128);
    }
#pragma unroll
    for (int nt = 0; nt < 4; ++nt) {
      int n = n0 + nt * 16 + lo;
      int yy = div48(n), xx = n - yy * SW;
      ushort4 ov;
      float vals[4];
#pragma unroll
      for (int reg = 0; reg < 4; ++reg) {
        float tv = (usey[reg] ? (float)yy : (float)xx) * dv[reg];
        float pe = usecos[reg] ? cosf(tv) : sinf(tv);
        vals[reg] = (acc[nt][reg] + bi[reg] + pe) * sc;
      }
      ov.x = f2bf(vals[0]); ov.y = f2bf(vals[1]);
      ov.z = f2bf(vals[2]); ov.w = f2bf(vals[3]);
      *(ushort4*)(base + (size_t)n * DK + d0) = ov;
    }
  }
}

// ---------------------------------------------------------------------------
// MFMA flash attention — R5 structure verbatim (best measured: 63.5 us).
// Only change: aot written in swizzled layout for out_kernel's coalesced reads.
// grid (36, 8, 2), block 256.
__global__ __launch_bounds__(256) void attn_kernel(
    const u16* __restrict__ qt, const u16* __restrict__ ktb,
    const u16* __restrict__ vb, const u16* __restrict__ dtabb,
    u16* __restrict__ aot) {
  int t = threadIdx.x;
  int w = t >> 6;
  int lane = t & 63;
  int lo = lane & 15, quad = lane >> 4;
  int n0 = blockIdx.x * 64;
  int h = blockIdx.y, b = blockIdx.z;

  __shared__ __align__(16) u16 dsh[DTAB_N];  // 18064 B
  __shared__ u16 Ks[64 * 40];
  __shared__ u16 Vs[32 * 72];
  __shared__ u16 Ps[4 * 16 * 72];

  for (int i = t; i < DTAB_N / 8; i += 256)
    *(uint4*)&dsh[i * 8] = *(const uint4*)&dtabb[i * 8];

  const u16* qtg = qt + (size_t)(b * NHEADS + h) * HW * DK;
  const u16* ktg = ktb + (size_t)(b * NHEADS + h) * HW * DK;
  const u16* vbg = vb + (size_t)(b * DMODEL + h * DK) * HW;

  short8 qf = *(const short8*)(qtg + (size_t)(n0 + w * 16 + lo) * DK + quad * 8);

  int a_i[4];
#pragma unroll
  for (int reg = 0; reg < 4; ++reg) {
    int n = n0 + w * 16 + quad * 4 + reg;
    int y1 = div48(n), x1 = n - y1 * SW;
    a_i[reg] = y1 * 95 + x1 + 4512;
  }

  f32x4 o0 = {0.f, 0.f, 0.f, 0.f}, o1 = {0.f, 0.f, 0.f, 0.f};
  float lsum[4] = {0.f, 0.f, 0.f, 0.f};
  u16* psw = Ps + w * 16 * 72;

  for (int kt = 0; kt < 36; ++kt) {
    int m0 = kt * 64;
    __syncthreads();  // prev PV reads done (and, on iter 0, dtab staged)
    {
      int row = t >> 2, c8 = (t & 3) * 8;
      *(uint4*)&Ks[row * 40 + c8] =
          *(const uint4*)(ktg + (size_t)(m0 + row) * DK + c8);
      int dd = t >> 3, mo = (t & 7) * 8;
      *(uint4*)&Vs[dd * 72 + mo] =
          *(const uint4*)(vbg + (size_t)dd * HW + m0 + mo);
    }
    __syncthreads();

    f32x4 s[4];
#pragma unroll
    for (int t4 = 0; t4 < 4; ++t4) {
      short8 kf = *(const short8*)&Ks[(t4 * 16 + lo) * 40 + quad * 8];
      f32x4 z = {0.f, 0.f, 0.f, 0.f};
      s[t4] = __builtin_amdgcn_mfma_f32_16x16x32_bf16(qf, kf, z, 0, 0, 0);
    }
#pragma unroll
    for (int t4 = 0; t4 < 4; ++t4) {
      int m = m0 + t4 * 16 + lo;
      int y2 = div48(m), x2 = m - y2 * SW;
      int bj = y2 * 95 + x2;
#pragma unroll
      for (int reg = 0; reg < 4; ++reg) {
        float p = __expf(s[t4][reg] + bf2f(dsh[a_i[reg] - bj]));
        lsum[reg] += p;
        psw[(quad * 4 + reg) * 72 + t4 * 16 + lo] = f2bf(p);
      }
    }
#pragma unroll
    for (int ks = 0; ks < 2; ++ks) {
      short8 af = *(const short8*)&psw[lo * 72 + ks * 32 + quad * 8];
      short8 v0 = *(const short8*)&Vs[lo * 72 + ks * 32 + quad * 8];
      o0 = __builtin_amdgcn_mfma_f32_16x16x32_bf16(af, v0, o0, 0, 0, 0);
      short8 v1 = *(const short8*)&Vs[(16 + lo) * 72 + ks * 32 + quad * 8];
      o1 = __builtin_amdgcn_mfma_f32_16x16x32_bf16(af, v1, o1, 0, 0, 0);
    }
  }

#pragma unroll
  for (int d = 1; d < 16; d <<= 1) {
#pragma unroll
    for (int reg = 0; reg < 4; ++reg) lsum[reg] += __shfl_xor(lsum[reg], d);
  }

  // write aot (swizzled, row=n, k=h*32+d), d = lo and 16+lo
  u16* aog = aot + (size_t)b * HW * DMODEL;
#pragma unroll
  for (int reg = 0; reg < 4; ++reg) {
    int n = n0 + w * 16 + quad * 4 + reg;
    float inv = 1.0f / lsum[reg];
    aog[swz(n, h * DK + lo)] = f2bf(o0[reg] * inv);
    aog[swz(n, h * DK + 16 + lo)] = f2bf(o1[reg] * inv);
  }
}

// ---------------------------------------------------------------------------
// out[b][c][n] = x + gamma * (Wo ao)[c][n] + bo[c], LDS-free MFMA GEMM with
// swizzled (fully coalesced) frag loads. grid (36, 4, 2), block 256.
__global__ __launch_bounds__(256) void out_kernel(
    const float* __restrict__ x, const u16* __restrict__ Wob,
    const float* __restrict__ bo, const float* __restrict__ gp,
    const u16* __restrict__ aot, float* __restrict__ out) {
  int t = threadIdx.x;
  int w = t >> 6, lane = t & 63, lo = lane & 15, quad = lane >> 4;
  int n0 = blockIdx.x * 64;
  int c0 = blockIdx.y * 64;
  int b = blockIdx.z;
  float gamma = gp[0];
  const u16* A = Wob + ((c0 + w * 16) >> 4) * 4096 + lo * 8;
  const u16* Ba = aot + (size_t)b * HW * DMODEL + lo * 8;

  f32x4 acc[4] = {{0.f, 0.f, 0.f, 0.f}, {0.f, 0.f, 0.f, 0.f},
                  {0.f, 0.f, 0.f, 0.f}, {0.f, 0.f, 0.f, 0.f}};
#pragma unroll
  for (int k0 = 0; k0 < DMODEL; k0 += 32) {
    int kblk = ((k0 >> 3) + quad) << 7;
    short8 af = *(const short8*)(A + kblk);
#pragma unroll
    for (int nt = 0; nt < 4; ++nt) {
      short8 bf_ = *(const short8*)(Ba + ((n0 + nt * 16) >> 4) * 4096 + kblk);
      acc[nt] = __builtin_amdgcn_mfma_f32_16x16x32_bf16(af, bf_, acc[nt], 0, 0, 0);
    }
  }

#pragma unroll
  for (int reg = 0; reg < 4; ++reg) {
    int c = c0 + w * 16 + quad * 4 + reg;
    float bi = bo[c];
    const float* xs = x + (size_t)(b * DMODEL + c) * HW + n0 + lo;
    float* os = out + (size_t)(b * DMODEL + c) * HW + n0 + lo;
#pragma unroll
    for (int nt = 0; nt < 4; ++nt)
      os[nt * 16] = xs[nt * 16] + gamma * acc[nt][reg] + bi;
  }
}

// ---------------------------------------------------------------------------
extern "C" void kernel_launch(void* const* d_in, const int* in_sizes, int n_in,
                              void* d_out, int out_size, void* d_ws,
                              size_t ws_size, hipStream_t stream) {
  const float* x   = (const float*)d_in[0];
  const float* Wq  = (const float*)d_in[1];
  const float* bq  = (const float*)d_in[2];
  const float* Wk  = (const float*)d_in[3];
  const float* bk  = (const float*)d_in[4];
  const float* Wv  = (const float*)d_in[5];
  const float* bv  = (const float*)d_in[6];
  const float* Wo  = (const float*)d_in[7];
  const float* bo  = (const float*)d_in[8];
  const float* lam = (const float*)d_in[9];
  const float* gam = (const float*)d_in[10];

  // ws layout (bytes), total ~10.0 MB:
  //   dtabb bf16 [0, 18064)           (region reserved to 36864)
  //   Wb    bf16 [36864, 561152)      4*65536*2, [q|k|v|o], swizzled
  //   xt    bf16 [561152, 2920448)    swizzled; ALIASED with aot
  //   qt    bf16 [2920448, 5279744)
  //   ktb   bf16 [5279744, 7639040)
  //   vb    bf16 [7639040, 9998336)
  char* wsb = (char*)d_ws;
  u16* dtabb = (u16*)wsb;
  u16* Wb  = (u16*)(wsb + 36864);
  u16* xt  = (u16*)(wsb + 561152);
  u16* aot = xt;  // alias, sequential lifetime
  u16* qt  = (u16*)(wsb + 2920448);
  u16* ktb = (u16*)(wsb + 5279744);
  u16* vb  = (u16*)(wsb + 7639040);
  float* out = (float*)d_out;

  prep_kernel<<<dim3(580), 256, 0, stream>>>(x, Wq, Wk, Wv, Wo, lam,
                                             xt, Wb, dtabb);
  qkv_kernel<<<dim3(36, 12, BATCH), 256, 0, stream>>>(Wb, xt, bq, bk, bv,
                                                      qt, ktb, vb);
  attn_kernel<<<dim3(36, NHEADS, BATCH), 256, 0, stream>>>(qt, ktb, vb, dtabb,
                                                           aot);
  out_kernel<<<dim3(36, 4, BATCH), 256, 0, stream>>>(x, Wb + 3 * 65536, bo, gam,
                                                     aot, out);
}

// Round 9
// 151.291 us; speedup vs baseline: 1.2337x; 1.0048x over previous
//
#include <hip/hip_runtime.h>

// Problem constants (B=2, C=256, H=W=48, d_model=256, 8 heads, d_k=32)
// Inputs/outputs fp32. Internals bf16; all matmuls + attention on MFMA.
// Wb / xt / aot live in MFMA-fragment-order swizzle:
//   addr(row,k) = (row>>4)*4096 + (k>>3)*128 + (row&15)*8 + (k&7)
// Distance bias lives in C-fragment-tile order:
//   Et[(m>>4)*144 + (q>>4)][(m&15)*16 + (q&15)]  (one 512B wave-load / 16-key tile)
#define HW 2304
#define SW 48
#define DMODEL 256
#define NHEADS 8
#define DK 32
#define BATCH 2

typedef unsigned short u16;
typedef __attribute__((ext_vector_type(8))) short short8;
typedef __attribute__((ext_vector_type(4))) float f32x4;

__device__ __forceinline__ float bf2f(u16 v) {
  union { unsigned int u; float f; } c; c.u = ((unsigned int)v) << 16; return c.f;
}
__device__ __forceinline__ float lo2f(unsigned int u) {
  union { unsigned int u; float f; } c; c.u = u << 16; return c.f;
}
__device__ __forceinline__ float hi2f(unsigned int u) {
  union { unsigned int u; float f; } c; c.u = u & 0xffff0000u; return c.f;
}
__device__ __forceinline__ u16 f2bf(float f) {
  union { unsigned int u; float f; } c; c.f = f;
  unsigned int u = c.u;
  unsigned int r = (u + 0x7FFFu + ((u >> 16) & 1u)) >> 16;
  return (u16)r;
}
// exact floor(n/48) for n in [0, 2304): magic 87382 = (2^22+32)/48
__device__ __forceinline__ int div48(int n) { return (n * 87382) >> 22; }
// fragment-order swizzle for a [rows][256] bf16 matrix
__device__ __forceinline__ int swz(int row, int k) {
  return ((row >> 4) << 12) + ((k >> 3) << 7) + ((row & 15) << 3) + (k & 7);
}

// ---------------------------------------------------------------------------
// Et bias table in C-fragment-tile order (see header). 2304x2304 bf16.
// Each thread computes 8 consecutive elements (same m, 8 consecutive q that
// never straddle a spatial row: q%48 in {0,8,16,24,32,40}).
// grid 2592, block 256.
__global__ __launch_bounds__(256) void eb_kernel(const float* __restrict__ lam_p,
                                                 u16* __restrict__ et) {
  int id = blockIdx.x * 256 + threadIdx.x;
  int flat = id * 8;
  int tile = flat >> 8;
  int within = flat & 255;
  int tm = tile / 144, tq = tile - tm * 144;
  int m = tm * 16 + (within >> 4);
  int q = tq * 16 + (within & 15);
  int ym = div48(m), xm = m - ym * SW;
  int yq = div48(q), xq = q - yq * SW;
  float lam = lam_p[0];
  float dy = (float)(yq - ym);
  float dy2 = dy * dy;
  u16 o[8];
#pragma unroll
  for (int j = 0; j < 8; ++j) {
    float dx = (float)(xq + j - xm);
    o[j] = f2bf(lam * __expf(-sqrtf(dy2 + dx * dx)));
  }
  *(uint4*)(et + flat) = *(const uint4*)o;
}

// ---------------------------------------------------------------------------
// prep: [0,288) transpose x -> xt (swizzled, row=n, k=c) bf16 ;
// [288,544) W fp32->bf16 swizzled, concat [q|k|v|o]. grid 544, block 256.
__global__ __launch_bounds__(256) void prep_kernel(
    const float* __restrict__ x,
    const float* __restrict__ Wq, const float* __restrict__ Wk,
    const float* __restrict__ Wv, const float* __restrict__ Wo,
    u16* __restrict__ xt, u16* __restrict__ Wb) {
  int bid = blockIdx.x;
  int t = threadIdx.x;
  if (bid < 288) {
    int b = bid / 144, r = bid % 144;
    int c0 = (r / 36) * 64, n0 = (r % 36) * 64;
    __shared__ u16 sh[64][72];  // [n][c]
#pragma unroll
    for (int p = 0; p < 4; ++p) {
      int row = (t >> 4) + p * 16;   // c
      int col4 = (t & 15) * 4;       // n
      float4 v = *(const float4*)(x + (size_t)(b * DMODEL + c0 + row) * HW +
                                  n0 + col4);
      sh[col4 + 0][row] = f2bf(v.x);
      sh[col4 + 1][row] = f2bf(v.y);
      sh[col4 + 2][row] = f2bf(v.z);
      sh[col4 + 3][row] = f2bf(v.w);
    }
    __syncthreads();
    u16* xtb = xt + (size_t)b * HW * DMODEL;
#pragma unroll
    for (int q = 0; q < 2; ++q) {
      int nrow = t >> 2;
      int c8 = (t & 3) * 8 + q * 32;
      *(uint4*)(xtb + swz(n0 + nrow, c0 + c8)) = *(const uint4*)&sh[nrow][c8];
    }
  } else {
    int idx = (bid - 288) * 1024 + t * 4;
    int which = idx >> 16, off = idx & 65535;
    int m = off >> 8, k = off & 255;
    const float* src = (which == 0) ? Wq : (which == 1) ? Wk
                       : (which == 2) ? Wv : Wo;
    float4 v = *(const float4*)(src + off);
    ushort4 ov;
    ov.x = f2bf(v.x); ov.y = f2bf(v.y); ov.z = f2bf(v.z); ov.w = f2bf(v.w);
    *(ushort4*)(Wb + which * 65536 + swz(m, k)) = ov;
  }
}

// ---------------------------------------------------------------------------
// QKV projection, LDS-free MFMA GEMM with swizzled (fully coalesced) frag
// loads. grid (36, 12, 2), block 256.
__global__ __launch_bounds__(256) void qkv_kernel(
    const u16* __restrict__ Wb, const u16* __restrict__ xt,
    const float* __restrict__ bq, const float* __restrict__ bk,
    const float* __restrict__ bv,
    u16* __restrict__ qt, u16* __restrict__ ktb, u16* __restrict__ vb) {
  int t = threadIdx.x;
  int w = t >> 6, lane = t & 63, lo = lane & 15, quad = lane >> 4;
  int n0 = blockIdx.x * 64;
  int mb = blockIdx.y, b = blockIdx.z;
  int which = mb >> 2;
  int mrel0 = (mb & 3) * 64;
  const u16* A = Wb + which * 65536 + ((mrel0 + w * 16) >> 4) * 4096 + lo * 8;
  const float* bias = (which == 0) ? bq : (which == 1) ? bk : bv;
  const u16* Bx = xt + (size_t)b * HW * DMODEL + lo * 8;

  f32x4 acc[4] = {{0.f, 0.f, 0.f, 0.f}, {0.f, 0.f, 0.f, 0.f},
                  {0.f, 0.f, 0.f, 0.f}, {0.f, 0.f, 0.f, 0.f}};
#pragma unroll
  for (int k0 = 0; k0 < DMODEL; k0 += 32) {
    int kblk = ((k0 >> 3) + quad) << 7;
    short8 af = *(const short8*)(A + kblk);
#pragma unroll
    for (int nt = 0; nt < 4; ++nt) {
      short8 bf_ = *(const short8*)(Bx + ((n0 + nt * 16) >> 4) * 4096 + kblk);
      acc[nt] = __builtin_amdgcn_mfma_f32_16x16x32_bf16(af, bf_, acc[nt], 0, 0, 0);
    }
  }

  int mbase = mrel0 + w * 16 + quad * 4;
  if (which == 2) {
#pragma unroll
    for (int reg = 0; reg < 4; ++reg) {
      int mrel = mbase + reg;
      float bi = bias[mrel];
      u16* dst = vb + (size_t)(b * DMODEL + mrel) * HW + n0 + lo;
#pragma unroll
      for (int nt = 0; nt < 4; ++nt) dst[nt * 16] = f2bf(acc[nt][reg] + bi);
    }
  } else {
    float sc = (which == 0) ? 0.17677669529663687f : 1.0f;
    int h = mbase >> 5, d0 = mbase & 31;
    u16* base = ((which == 0) ? qt : ktb) + (size_t)(b * NHEADS + h) * HW * DK;
    float bi[4], dv[4];
    bool usecos[4], usey[4];
#pragma unroll
    for (int reg = 0; reg < 4; ++reg) {
      int mrel = mbase + reg;
      bi[reg] = bias[mrel];
      int oo = mrel & 127;
      dv[reg] = expf(-0.07195578415606394f * (float)(oo & ~1));
      usecos[reg] = (oo & 1);
      usey[reg] = (mrel >= 128);
    }
#pragma unroll
    for (int nt = 0; nt < 4; ++nt) {
      int n = n0 + nt * 16 + lo;
      int yy = div48(n), xx = n - yy * SW;
      ushort4 ov;
      float vals[4];
#pragma unroll
      for (int reg = 0; reg < 4; ++reg) {
        float tv = (usey[reg] ? (float)yy : (float)xx) * dv[reg];
        float pe = usecos[reg] ? cosf(tv) : sinf(tv);
        vals[reg] = (acc[nt][reg] + bi[reg] + pe) * sc;
      }
      ov.x = f2bf(vals[0]); ov.y = f2bf(vals[1]);
      ov.z = f2bf(vals[2]); ov.w = f2bf(vals[3]);
      *(ushort4*)(base + (size_t)n * DK + d0) = ov;
    }
  }
}

// ---------------------------------------------------------------------------
// MFMA flash attention — R5 structure; bias via coalesced Et uint2 loads
// (replaces the in-loop LDS dtab gathers; dsh/staging deleted).
// grid (36, 8, 2), block 256.
__global__ __launch_bounds__(256) void attn_kernel(
    const u16* __restrict__ qt, const u16* __restrict__ ktb,
    const u16* __restrict__ vb, const u16* __restrict__ et,
    u16* __restrict__ aot) {
  int t = threadIdx.x;
  int w = t >> 6;
  int lane = t & 63;
  int lo = lane & 15, quad = lane >> 4;
  int n0 = blockIdx.x * 64;
  int h = blockIdx.y, b = blockIdx.z;

  __shared__ u16 Ks[64 * 40];
  __shared__ u16 Vs[32 * 72];
  __shared__ u16 Ps[4 * 16 * 72];

  const u16* qtg = qt + (size_t)(b * NHEADS + h) * HW * DK;
  const u16* ktg = ktb + (size_t)(b * NHEADS + h) * HW * DK;
  const u16* vbg = vb + (size_t)(b * DMODEL + h * DK) * HW;

  short8 qf = *(const short8*)(qtg + (size_t)(n0 + w * 16 + lo) * DK + quad * 8);

  // bias pointer for this wave's q-tile: Et[tile=tm*144+tq][lo*16+quad*4]
  int tq = (n0 >> 4) + w;
  const u16* etw = et + (size_t)tq * 256 + lo * 16 + quad * 4;

  f32x4 o0 = {0.f, 0.f, 0.f, 0.f}, o1 = {0.f, 0.f, 0.f, 0.f};
  float lsum[4] = {0.f, 0.f, 0.f, 0.f};
  u16* psw = Ps + w * 16 * 72;

  for (int kt = 0; kt < 36; ++kt) {
    int m0 = kt * 64;
    __syncthreads();  // prev PV reads done before restaging
    {
      int row = t >> 2, c8 = (t & 3) * 8;
      *(uint4*)&Ks[row * 40 + c8] =
          *(const uint4*)(ktg + (size_t)(m0 + row) * DK + c8);
      int dd = t >> 3, mo = (t & 7) * 8;
      *(uint4*)&Vs[dd * 72 + mo] =
          *(const uint4*)(vbg + (size_t)dd * HW + m0 + mo);
    }
    __syncthreads();

    // bias loads (independent of MFMA; 512B contiguous per wave per t4)
    uint2 ebv[4];
#pragma unroll
    for (int t4 = 0; t4 < 4; ++t4)
      ebv[t4] = *(const uint2*)(etw + (size_t)((m0 >> 4) + t4) * 36864);

    f32x4 s[4];
#pragma unroll
    for (int t4 = 0; t4 < 4; ++t4) {
      short8 kf = *(const short8*)&Ks[(t4 * 16 + lo) * 40 + quad * 8];
      f32x4 z = {0.f, 0.f, 0.f, 0.f};
      s[t4] = __builtin_amdgcn_mfma_f32_16x16x32_bf16(qf, kf, z, 0, 0, 0);
    }
#pragma unroll
    for (int t4 = 0; t4 < 4; ++t4) {
      float p0 = __expf(s[t4][0] + lo2f(ebv[t4].x));
      float p1 = __expf(s[t4][1] + hi2f(ebv[t4].x));
      float p2 = __expf(s[t4][2] + lo2f(ebv[t4].y));
      float p3 = __expf(s[t4][3] + hi2f(ebv[t4].y));
      lsum[0] += p0; lsum[1] += p1; lsum[2] += p2; lsum[3] += p3;
      psw[(quad * 4 + 0) * 72 + t4 * 16 + lo] = f2bf(p0);
      psw[(quad * 4 + 1) * 72 + t4 * 16 + lo] = f2bf(p1);
      psw[(quad * 4 + 2) * 72 + t4 * 16 + lo] = f2bf(p2);
      psw[(quad * 4 + 3) * 72 + t4 * 16 + lo] = f2bf(p3);
    }
#pragma unroll
    for (int ks = 0; ks < 2; ++ks) {
      short8 af = *(const short8*)&psw[lo * 72 + ks * 32 + quad * 8];
      short8 v0 = *(const short8*)&Vs[lo * 72 + ks * 32 + quad * 8];
      o0 = __builtin_amdgcn_mfma_f32_16x16x32_bf16(af, v0, o0, 0, 0, 0);
      short8 v1 = *(const short8*)&Vs[(16 + lo) * 72 + ks * 32 + quad * 8];
      o1 = __builtin_amdgcn_mfma_f32_16x16x32_bf16(af, v1, o1, 0, 0, 0);
    }
  }

#pragma unroll
  for (int d = 1; d < 16; d <<= 1) {
#pragma unroll
    for (int reg = 0; reg < 4; ++reg) lsum[reg] += __shfl_xor(lsum[reg], d);
  }

  // write aot (swizzled, row=n, k=h*32+d), d = lo and 16+lo
  u16* aog = aot + (size_t)b * HW * DMODEL;
#pragma unroll
  for (int reg = 0; reg < 4; ++reg) {
    int n = n0 + w * 16 + quad * 4 + reg;
    float inv = 1.0f / lsum[reg];
    aog[swz(n, h * DK + lo)] = f2bf(o0[reg] * inv);
    aog[swz(n, h * DK + 16 + lo)] = f2bf(o1[reg] * inv);
  }
}

// ---------------------------------------------------------------------------
// out[b][c][n] = x + gamma * (Wo ao)[c][n] + bo[c], LDS-free MFMA GEMM with
// swizzled (fully coalesced) frag loads. grid (36, 4, 2), block 256.
__global__ __launch_bounds__(256) void out_kernel(
    const float* __restrict__ x, const u16* __restrict__ Wob,
    const float* __restrict__ bo, const float* __restrict__ gp,
    const u16* __restrict__ aot, float* __restrict__ out) {
  int t = threadIdx.x;
  int w = t >> 6, lane = t & 63, lo = lane & 15, quad = lane >> 4;
  int n0 = blockIdx.x * 64;
  int c0 = blockIdx.y * 64;
  int b = blockIdx.z;
  float gamma = gp[0];
  const u16* A = Wob + ((c0 + w * 16) >> 4) * 4096 + lo * 8;
  const u16* Ba = aot + (size_t)b * HW * DMODEL + lo * 8;

  f32x4 acc[4] = {{0.f, 0.f, 0.f, 0.f}, {0.f, 0.f, 0.f, 0.f},
                  {0.f, 0.f, 0.f, 0.f}, {0.f, 0.f, 0.f, 0.f}};
#pragma unroll
  for (int k0 = 0; k0 < DMODEL; k0 += 32) {
    int kblk = ((k0 >> 3) + quad) << 7;
    short8 af = *(const short8*)(A + kblk);
#pragma unroll
    for (int nt = 0; nt < 4; ++nt) {
      short8 bf_ = *(const short8*)(Ba + ((n0 + nt * 16) >> 4) * 4096 + kblk);
      acc[nt] = __builtin_amdgcn_mfma_f32_16x16x32_bf16(af, bf_, acc[nt], 0, 0, 0);
    }
  }

#pragma unroll
  for (int reg = 0; reg < 4; ++reg) {
    int c = c0 + w * 16 + quad * 4 + reg;
    float bi = bo[c];
    const float* xs = x + (size_t)(b * DMODEL + c) * HW + n0 + lo;
    float* os = out + (size_t)(b * DMODEL + c) * HW + n0 + lo;
#pragma unroll
    for (int nt = 0; nt < 4; ++nt)
      os[nt * 16] = xs[nt * 16] + gamma * acc[nt][reg] + bi;
  }
}

// ---------------------------------------------------------------------------
extern "C" void kernel_launch(void* const* d_in, const int* in_sizes, int n_in,
                              void* d_out, int out_size, void* d_ws,
                              size_t ws_size, hipStream_t stream) {
  const float* x   = (const float*)d_in[0];
  const float* Wq  = (const float*)d_in[1];
  const float* bq  = (const float*)d_in[2];
  const float* Wk  = (const float*)d_in[3];
  const float* bk  = (const float*)d_in[4];
  const float* Wv  = (const float*)d_in[5];
  const float* bv  = (const float*)d_in[6];
  const float* Wo  = (const float*)d_in[7];
  const float* bo  = (const float*)d_in[8];
  const float* lam = (const float*)d_in[9];
  const float* gam = (const float*)d_in[10];

  // ws layout (bytes), total ~20.6 MB (R7 ran clean through this span):
  //   (unused)   [0, 36864)
  //   Wb    bf16 [36864, 561152)      4*65536*2, [q|k|v|o], swizzled
  //   xt    bf16 [561152, 2920448)    swizzled; ALIASED with aot
  //   qt    bf16 [2920448, 5279744)
  //   ktb   bf16 [5279744, 7639040)
  //   vb    bf16 [7639040, 9998336)
  //   et    bf16 [9998336, 20615168)  2304*2304 bias, C-fragment-tile order
  char* wsb = (char*)d_ws;
  u16* Wb  = (u16*)(wsb + 36864);
  u16* xt  = (u16*)(wsb + 561152);
  u16* aot = xt;  // alias, sequential lifetime
  u16* qt  = (u16*)(wsb + 2920448);
  u16* ktb = (u16*)(wsb + 5279744);
  u16* vb  = (u16*)(wsb + 7639040);
  u16* et  = (u16*)(wsb + 9998336);
  float* out = (float*)d_out;

  eb_kernel<<<dim3(2592), 256, 0, stream>>>(lam, et);
  prep_kernel<<<dim3(544), 256, 0, stream>>>(x, Wq, Wk, Wv, Wo, xt, Wb);
  qkv_kernel<<<dim3(36, 12, BATCH), 256, 0, stream>>>(Wb, xt, bq, bk, bv,
                                                      qt, ktb, vb);
  attn_kernel<<<dim3(36, NHEADS, BATCH), 256, 0, stream>>>(qt, ktb, vb, et,
                                                           aot);
  out_kernel<<<dim3(36, 4, BATCH), 256, 0, stream>>>(x, Wb + 3 * 65536, bo, gam,
                                                     aot, out);
}